// Round 9
// baseline (302.889 us; speedup 1.0000x reference)
//
#include <hip/hip_runtime.h>
#include <stdint.h>

#define NN 4096
#define EPSV 1e-7f
#define SLABC 512          // columns per slab; f16 slab 4 MB, fp8 slab 2 MB (per-XCD L2-resident)
#define NSLAB (NN / SLABC) // 8 slabs = 8 XCDs

typedef short shortx4 __attribute__((ext_vector_type(4)));
typedef float floatx2 __attribute__((ext_vector_type(2)));
typedef float floatx4 __attribute__((ext_vector_type(4)));
typedef unsigned int uintx4 __attribute__((ext_vector_type(4)));
typedef _Float16 half2t __attribute__((ext_vector_type(2)));

static __device__ __forceinline__ short f2h(float f) {
    union { _Float16 h; short s; } c;
    c.h = (_Float16)f;
    return c.s;
}

// d += dot(2xf16(a), 2xf16(b)); folds to v_fma_mix_f32 (verified round 6 by
// VALU cycle accounting).
static __device__ __forceinline__ float dot2acc(unsigned a, unsigned b, float d) {
    union { unsigned u; half2t h; } ua, ub;
    ua.u = a; ub.u = b;
    d = fmaf((float)ua.h[0], (float)ub.h[0], d);
    return fmaf((float)ua.h[1], (float)ub.h[1], d);
}

// d += dot(4xfp8(v), 4xf16(h0:h1)); cvt_pk unpack + fma_mix.
static __device__ __forceinline__ float fp8dot4(unsigned v, unsigned h0, unsigned h1, float d) {
    floatx2 lo = __builtin_amdgcn_cvt_pk_f32_fp8(v, false);
    floatx2 hi = __builtin_amdgcn_cvt_pk_f32_fp8(v, true);
    union { unsigned u; half2t h; } a, b;
    a.u = h0; b.u = h1;
    d = fmaf(lo[0], (float)a.h[0], d);
    d = fmaf(lo[1], (float)a.h[1], d);
    d = fmaf(hi[0], (float)b.h[0], d);
    return fmaf(hi[1], (float)b.h[1], d);
}

// wave-uniform value -> SGPR (compiler hint): scalar addressing + SALU math.
static __device__ __forceinline__ int rfl_i(int v) {
    return __builtin_amdgcn_readfirstlane(v);
}
static __device__ __forceinline__ float rfl_f(float v) {
    union { float f; int i; } u;
    u.f = v;
    u.i = __builtin_amdgcn_readfirstlane(u.i);
    return u.f;
}

// Fused prep: blocks [0,1024) cast x (f32) -> xh (f16) [+ xf8 fp8] + nsq col
// sumsq; blocks [1024,5120) compact adj row (bid-1024) into a sorted index
// list. One launch: the two streaming passes overlap. Plain loads (NT hints
// removed: never counter-validated; NT was the one measured regression in r3).
__global__ __launch_bounds__(256) void prep(const float* __restrict__ x,
                                            const float* __restrict__ adj,
                                            short* __restrict__ xh,
                                            unsigned char* __restrict__ xf8,  // may be null
                                            float* __restrict__ nsq,
                                            unsigned short* __restrict__ idx,
                                            int* __restrict__ cnt) {
    __shared__ floatx4 cs[4][64];
    __shared__ int wtot[4];
    const int bid = blockIdx.x;
    const int t = threadIdx.x;
    const int lane = t & 63;
    const int w = t >> 6;

    if (bid < 1024) {  // ---- cast role ----
        const int cb = (bid & 15) * 256;
        const int rb = (bid >> 4) * 64;
        const int col = cb + lane * 4;
        floatx4 ss = {0.f, 0.f, 0.f, 0.f};
#pragma unroll
        for (int i = 0; i < 16; ++i) {
            const int r = rb + w + i * 4;
            floatx4 v = *(const floatx4*)(x + (size_t)r * NN + col);
            ss += v * v;
            shortx4 o;
            o[0] = f2h(v[0]); o[1] = f2h(v[1]); o[2] = f2h(v[2]); o[3] = f2h(v[3]);
            *(shortx4*)(xh + (size_t)r * NN + col) = o;
            if (xf8) {  // uniform branch
                int p = __builtin_amdgcn_cvt_pk_fp8_f32(v[0], v[1], 0, false);
                p = __builtin_amdgcn_cvt_pk_fp8_f32(v[2], v[3], p, true);
                *(int*)(xf8 + (size_t)r * NN + col) = p;
            }
        }
        cs[w][lane] = ss;
        __syncthreads();
        if (w == 0) {
            floatx4 s4 = cs[0][lane] + cs[1][lane] + cs[2][lane] + cs[3][lane];
            float* np = nsq + col;
            atomicAdd(np + 0, s4[0]);
            atomicAdd(np + 1, s4[1]);
            atomicAdd(np + 2, s4[2]);
            atomicAdd(np + 3, s4[3]);
        }
    } else {  // ---- index role: row i, sorted prefix-sum compaction ----
        const size_t i = (size_t)(bid - 1024);
        const floatx4* ar = (const floatx4*)(adj + i * NN) + 4 * t;
        floatx4 a0 = ar[0];
        floatx4 a1 = ar[1];
        floatx4 a2 = ar[2];
        floatx4 a3 = ar[3];
        unsigned mask = 0;
#pragma unroll
        for (int u = 0; u < 4; ++u) {
            floatx4 a = (u == 0) ? a0 : (u == 1) ? a1 : (u == 2) ? a2 : a3;
#pragma unroll
            for (int e = 0; e < 4; ++e)
                if (a[e] != 0.f) mask |= 1u << (4 * u + e);
        }
        const int h = __popc(mask);
        int sc = h;  // wave-inclusive scan
#pragma unroll
        for (int o = 1; o < 64; o <<= 1) {
            int v = __shfl_up(sc, o, 64);
            if (lane >= o) sc += v;
        }
        if (lane == 63) wtot[w] = sc;
        __syncthreads();
        int base = 0;
#pragma unroll
        for (int ww = 0; ww < 4; ++ww)
            if (ww < w) base += wtot[ww];
        int c = wtot[0] + wtot[1] + wtot[2] + wtot[3];
        if (c > 256) c = 256;
        if (t == 0) cnt[i] = c;
        int off = base + sc - h;  // exclusive prefix
        unsigned m = mask;
        while (m) {
            int b = __ffs(m) - 1;
            m &= m - 1;
            if (off < 256) idx[i * 256 + off] = (unsigned short)(16 * t + b);
            ++off;
        }
    }
}

// Partial scores for one (i-quad, slab), fp8 j-rows vs f16 x_i (r8-measured
// structure, met prediction — unchanged).
__global__ __launch_bounds__(256) void score_slab_fp8(const unsigned char* __restrict__ x8,
                                                      const short* __restrict__ xh,
                                                      const unsigned short* __restrict__ idx,
                                                      const int* __restrict__ cnt,
                                                      float* __restrict__ score) {
    const int t = threadIdx.x;
    const int lane = t & 63;
    const int w = t >> 6;
    const int g = lane >> 3;  // k-group within round
    const int sl = lane & 7;  // column sub-chunk
    const int col0 = blockIdx.x * SLABC;
    const size_t i = (size_t)blockIdx.y * 4 + w;
    const int c = cnt[i];
    const unsigned short* irow = idx + i * 256;

    const uintx4* xr = (const uintx4*)(xh + i * NN + col0);
    uintx4 xiA[4], xiB[4];
#pragma unroll
    for (int it = 0; it < 4; ++it) {
        const int m = it * 8 + sl;
        xiA[it] = xr[2 * m];
        xiB[it] = xr[2 * m + 1];
    }

    for (int r = 0; r * 8 < c; ++r) {
        const int k = r * 8 + g;
        const bool ok = k < c;
        const int kk = ok ? k : c - 1;
        const int j = irow[kk];
        const uintx4* rp = (const uintx4*)(x8 + (size_t)j * NN + col0);
        uintx4 v0 = rp[sl], v1 = rp[8 + sl], v2 = rp[16 + sl], v3 = rp[24 + sl];
        float d0 = 0.f, d1 = 0.f, d2 = 0.f, d3 = 0.f;
#pragma unroll
        for (int q = 0; q < 4; ++q) {
            const unsigned hA0 = (q < 2) ? xiA[0][2 * q] : xiB[0][2 * (q - 2)];
            const unsigned hA1 = (q < 2) ? xiA[0][2 * q + 1] : xiB[0][2 * (q - 2) + 1];
            d0 = fp8dot4(v0[q], hA0, hA1, d0);
            const unsigned hB0 = (q < 2) ? xiA[1][2 * q] : xiB[1][2 * (q - 2)];
            const unsigned hB1 = (q < 2) ? xiA[1][2 * q + 1] : xiB[1][2 * (q - 2) + 1];
            d1 = fp8dot4(v1[q], hB0, hB1, d1);
            const unsigned hC0 = (q < 2) ? xiA[2][2 * q] : xiB[2][2 * (q - 2)];
            const unsigned hC1 = (q < 2) ? xiA[2][2 * q + 1] : xiB[2][2 * (q - 2) + 1];
            d2 = fp8dot4(v2[q], hC0, hC1, d2);
            const unsigned hD0 = (q < 2) ? xiA[3][2 * q] : xiB[3][2 * (q - 2)];
            const unsigned hD1 = (q < 2) ? xiA[3][2 * q + 1] : xiB[3][2 * (q - 2) + 1];
            d3 = fp8dot4(v3[q], hD0, hD1, d3);
        }
        float d = (d0 + d1) + (d2 + d3);
        d += __shfl_xor(d, 1, 64);
        d += __shfl_xor(d, 2, 64);
        d += __shfl_xor(d, 4, 64);
        if (ok && sl == 0) atomicAdd(&score[i * 256 + k], d);
    }
}

// f16 fallback (r6-measured structure) for tight workspaces.
__global__ __launch_bounds__(256) void score_slab_f16(const short* __restrict__ xh,
                                                      const unsigned short* __restrict__ idx,
                                                      const int* __restrict__ cnt,
                                                      float* __restrict__ score) {
    const int t = threadIdx.x;
    const int lane = t & 63;
    const int w = t >> 6;
    const int g = lane >> 3;
    const int sl = lane & 7;
    const int col0 = blockIdx.x * SLABC;
    const size_t i = (size_t)blockIdx.y * 4 + w;
    const int c = cnt[i];
    const unsigned short* irow = idx + i * 256;

    const uintx4* xr = (const uintx4*)(xh + i * NN + col0);
    uintx4 xi[8];
#pragma unroll
    for (int it = 0; it < 8; ++it) xi[it] = xr[it * 8 + sl];

    for (int r = 0; r * 8 < c; ++r) {
        const int k = r * 8 + g;
        const bool ok = k < c;
        const int kk = ok ? k : c - 1;
        const int j = irow[kk];
        const uintx4* rp = (const uintx4*)(xh + (size_t)j * NN + col0);
        uintx4 v0 = rp[sl], v1 = rp[8 + sl], v2 = rp[16 + sl], v3 = rp[24 + sl];
        uintx4 v4 = rp[32 + sl], v5 = rp[40 + sl], v6 = rp[48 + sl], v7 = rp[56 + sl];
        float d0 = 0.f, d1 = 0.f, d2 = 0.f, d3 = 0.f;
#pragma unroll
        for (int u = 0; u < 4; ++u) {
            d0 = dot2acc(v0[u], xi[0][u], d0);
            d1 = dot2acc(v1[u], xi[1][u], d1);
            d2 = dot2acc(v2[u], xi[2][u], d2);
            d3 = dot2acc(v3[u], xi[3][u], d3);
            d0 = dot2acc(v4[u], xi[4][u], d0);
            d1 = dot2acc(v5[u], xi[5][u], d1);
            d2 = dot2acc(v6[u], xi[6][u], d2);
            d3 = dot2acc(v7[u], xi[7][u], d3);
        }
        float d = (d0 + d1) + (d2 + d3);
        d += __shfl_xor(d, 1, 64);
        d += __shfl_xor(d, 2, 64);
        d += __shfl_xor(d, 4, 64);
        if (ok && sl == 0) atomicAdd(&score[i * 256 + k], d);
    }
}

// PV for one (i-quad, slab). Wave w owns i = 4*by+w: per-wave softmax, then
// k-loop with SGPR-hoisted j,p (readfirstlane: j -> SALU address + saddr
// loads; p -> the one SGPR operand of v_fma_mix) and a 4+4 software pipeline
// (pv is not VGPR-tight: 28 VGPR in r8, +16 stays under the 64-VGPR cliff).
__global__ __launch_bounds__(256) void pv_slab(const short* __restrict__ xh,
                                               const float* __restrict__ nsq,
                                               const unsigned short* __restrict__ idx,
                                               const int* __restrict__ cnt,
                                               const float* __restrict__ score,
                                               const float* __restrict__ betaPtr,
                                               float* __restrict__ out) {
    __shared__ float svs[4][256];
    __shared__ unsigned short jds[4][256];
    const int t = threadIdx.x;
    const int lane = t & 63;
    const int w = t >> 6;
    const int col0 = blockIdx.x * SLABC;
    const size_t i = (size_t)blockIdx.y * 4 + w;
    const int c = cnt[i];
    const float beta = *betaPtr;
    const float ni = sqrtf(nsq[i]);

    // per-wave softmax over sv[0..c) (masked entries contribute exactly 0, as in ref)
    float sreg[4];
    int jreg[4];
#pragma unroll
    for (int q = 0; q < 4; ++q) {
        const int k = lane + 64 * q;
        if (k < c) {
            const int j = idx[i * 256 + k];
            jreg[q] = j;
            sreg[q] = beta * score[i * 256 + k] / (ni * sqrtf(nsq[j]) + EPSV);
        } else {
            jreg[q] = 0;
            sreg[q] = -3.0e38f;
        }
    }
    float mx = fmaxf(fmaxf(sreg[0], sreg[1]), fmaxf(sreg[2], sreg[3]));
#pragma unroll
    for (int off = 32; off; off >>= 1) mx = fmaxf(mx, __shfl_xor(mx, off, 64));
    float sm = 0.f;
#pragma unroll
    for (int q = 0; q < 4; ++q) {
        const int k = lane + 64 * q;
        float e = (k < c) ? __expf(sreg[q] - mx) : 0.f;
        sreg[q] = e;
        sm += e;
    }
#pragma unroll
    for (int off = 32; off; off >>= 1) sm += __shfl_xor(sm, off, 64);
    const float inv = 1.f / sm;
#pragma unroll
    for (int q = 0; q < 4; ++q) {
        const int k = lane + 64 * q;
        svs[w][k] = sreg[q] * inv;
        jds[w][k] = (unsigned short)jreg[q];
    }
    __syncthreads();  // uniform; fences LDS

    const short* xcol = xh + col0 + lane * 8;
    // wave-uniform j,p via readfirstlane -> SGPR (clamped index / zero weight
    // past c: tail prefetches are harmless L2 hits of row c-1)
    auto jof = [&](int kk) -> int { return rfl_i((int)jds[w][kk < c ? kk : c - 1]); };
    auto pof = [&](int kk) -> float { return rfl_f(kk < c ? svs[w][kk] : 0.f); };

    float acc[8];
#pragma unroll
    for (int e = 0; e < 8; ++e) acc[e] = 0.f;

    // prefetch k = 0..3 (c >= 1 always: self-loop)
    int j0 = jof(0), j1 = jof(1), j2 = jof(2), j3 = jof(3);
    uintx4 v0 = *(const uintx4*)(xcol + (size_t)j0 * NN);
    uintx4 v1 = *(const uintx4*)(xcol + (size_t)j1 * NN);
    uintx4 v2 = *(const uintx4*)(xcol + (size_t)j2 * NN);
    uintx4 v3 = *(const uintx4*)(xcol + (size_t)j3 * NN);

    for (int k = 0; k < c; k += 4) {
        const int n0 = jof(k + 4), n1 = jof(k + 5), n2 = jof(k + 6), n3 = jof(k + 7);
        uintx4 w0 = *(const uintx4*)(xcol + (size_t)n0 * NN);
        uintx4 w1 = *(const uintx4*)(xcol + (size_t)n1 * NN);
        uintx4 w2 = *(const uintx4*)(xcol + (size_t)n2 * NN);
        uintx4 w3 = *(const uintx4*)(xcol + (size_t)n3 * NN);

        const float p0 = pof(k), p1 = pof(k + 1), p2 = pof(k + 2), p3 = pof(k + 3);
#pragma unroll
        for (int u = 0; u < 4; ++u) {
            union { unsigned x; half2t h; } c0, c1, c2, c3;
            c0.x = v0[u]; c1.x = v1[u]; c2.x = v2[u]; c3.x = v3[u];
            float a0 = acc[2 * u], a1 = acc[2 * u + 1];
            a0 = fmaf(p0, (float)c0.h[0], a0); a1 = fmaf(p0, (float)c0.h[1], a1);
            a0 = fmaf(p1, (float)c1.h[0], a0); a1 = fmaf(p1, (float)c1.h[1], a1);
            a0 = fmaf(p2, (float)c2.h[0], a0); a1 = fmaf(p2, (float)c2.h[1], a1);
            a0 = fmaf(p3, (float)c3.h[0], a0); a1 = fmaf(p3, (float)c3.h[1], a1);
            acc[2 * u] = a0; acc[2 * u + 1] = a1;
        }
        v0 = w0; v1 = w1; v2 = w2; v3 = w3;
    }

    floatx4* op = (floatx4*)(out + i * NN + col0 + lane * 8);
    floatx4 o0 = {acc[0], acc[1], acc[2], acc[3]};
    floatx4 o1 = {acc[4], acc[5], acc[6], acc[7]};
    __builtin_nontemporal_store(o0, op + 0);
    __builtin_nontemporal_store(o1, op + 1);
}

extern "C" void kernel_launch(void* const* d_in, const int* in_sizes, int n_in,
                              void* d_out, int out_size, void* d_ws, size_t ws_size,
                              hipStream_t stream) {
    const float* x = (const float*)d_in[0];
    const float* adj = (const float*)d_in[1];
    const float* beta = (const float*)d_in[2];

    const size_t XH = (size_t)32 * 1024 * 1024;   // f16 x
    const size_t IX = (size_t)2 * 1024 * 1024;    // u16 idx [4096][256]
    const size_t SC = (size_t)4 * 1024 * 1024;    // f32 score [4096][256]
    const size_t XF8 = (size_t)16 * 1024 * 1024;  // fp8 x (optional, at end)
    const size_t base = XH + IX + SC + 2 * NN * sizeof(float);
    if (ws_size < base) return;  // ~38 MB
    const bool use_fp8 = ws_size >= base + XF8;  // ~54 MB

    char* ws = (char*)d_ws;
    short* xh = (short*)ws;
    unsigned short* idx = (unsigned short*)(ws + XH);
    float* score = (float*)(ws + XH + IX);
    float* nsq = (float*)(ws + XH + IX + SC);
    int* cnt = (int*)(ws + XH + IX + SC + NN * sizeof(float));
    unsigned char* xf8 = use_fp8 ? (unsigned char*)(ws + base) : nullptr;

    (void)hipMemsetAsync(nsq, 0, NN * sizeof(float), stream);
    (void)hipMemsetAsync(score, 0, SC, stream);
    prep<<<1024 + NN, 256, 0, stream>>>(x, adj, xh, xf8, nsq, idx, cnt);
    if (use_fp8)
        score_slab_fp8<<<dim3(NSLAB, NN / 4), 256, 0, stream>>>(xf8, xh, idx, cnt, score);
    else
        score_slab_f16<<<dim3(NSLAB, NN / 4), 256, 0, stream>>>(xh, idx, cnt, score);
    pv_slab<<<dim3(NSLAB, NN / 4), 256, 0, stream>>>(xh, nsq, idx, cnt, score, beta, (float*)d_out);
}

// Round 10
// 295.868 us; speedup vs baseline: 1.0237x; 1.0237x over previous
//
#include <hip/hip_runtime.h>
#include <stdint.h>

#define NN 4096
#define EPSV 1e-7f
#define SLABC 512          // columns per slab; f16 slab 4 MB, fp8 slab 2 MB (per-XCD L2-resident)
#define NSLAB (NN / SLABC) // 8 slabs = 8 XCDs

typedef short shortx4 __attribute__((ext_vector_type(4)));
typedef float floatx2 __attribute__((ext_vector_type(2)));
typedef float floatx4 __attribute__((ext_vector_type(4)));
typedef unsigned int uintx4 __attribute__((ext_vector_type(4)));
typedef _Float16 half2t __attribute__((ext_vector_type(2)));

static __device__ __forceinline__ short f2h(float f) {
    union { _Float16 h; short s; } c;
    c.h = (_Float16)f;
    return c.s;
}

// d += dot(2xf16(a), 2xf16(b)); folds to v_fma_mix_f32 (verified round 6 by
// VALU cycle accounting).
static __device__ __forceinline__ float dot2acc(unsigned a, unsigned b, float d) {
    union { unsigned u; half2t h; } ua, ub;
    ua.u = a; ub.u = b;
    d = fmaf((float)ua.h[0], (float)ub.h[0], d);
    return fmaf((float)ua.h[1], (float)ub.h[1], d);
}

// d += dot(4xfp8(v), 4xf16(h0:h1)); cvt_pk unpack + fma_mix.
static __device__ __forceinline__ float fp8dot4(unsigned v, unsigned h0, unsigned h1, float d) {
    floatx2 lo = __builtin_amdgcn_cvt_pk_f32_fp8(v, false);
    floatx2 hi = __builtin_amdgcn_cvt_pk_f32_fp8(v, true);
    union { unsigned u; half2t h; } a, b;
    a.u = h0; b.u = h1;
    d = fmaf(lo[0], (float)a.h[0], d);
    d = fmaf(lo[1], (float)a.h[1], d);
    d = fmaf(hi[0], (float)b.h[0], d);
    return fmaf(hi[1], (float)b.h[1], d);
}

// Fused prep: blocks [0,1024) cast x (f32) -> xh (f16) [+ xf8 fp8] + nsq col
// sumsq; blocks [1024,5120) zero score row + compact adj row (bid-1024) into
// a sorted index list. One launch: the two streaming passes overlap, and the
// score-zeroing rides along (replaces a 4 MB memset launch).
__global__ __launch_bounds__(256) void prep(const float* __restrict__ x,
                                            const float* __restrict__ adj,
                                            short* __restrict__ xh,
                                            unsigned char* __restrict__ xf8,  // may be null
                                            float* __restrict__ nsq,
                                            unsigned short* __restrict__ idx,
                                            int* __restrict__ cnt,
                                            float* __restrict__ score) {
    __shared__ floatx4 cs[4][64];
    __shared__ int wtot[4];
    const int bid = blockIdx.x;
    const int t = threadIdx.x;
    const int lane = t & 63;
    const int w = t >> 6;

    if (bid < 1024) {  // ---- cast role ----
        const int cb = (bid & 15) * 256;
        const int rb = (bid >> 4) * 64;
        const int col = cb + lane * 4;
        floatx4 ss = {0.f, 0.f, 0.f, 0.f};
#pragma unroll
        for (int i = 0; i < 16; ++i) {
            const int r = rb + w + i * 4;
            floatx4 v = *(const floatx4*)(x + (size_t)r * NN + col);
            ss += v * v;
            shortx4 o;
            o[0] = f2h(v[0]); o[1] = f2h(v[1]); o[2] = f2h(v[2]); o[3] = f2h(v[3]);
            *(shortx4*)(xh + (size_t)r * NN + col) = o;
            if (xf8) {  // uniform branch
                int p = __builtin_amdgcn_cvt_pk_fp8_f32(v[0], v[1], 0, false);
                p = __builtin_amdgcn_cvt_pk_fp8_f32(v[2], v[3], p, true);
                *(int*)(xf8 + (size_t)r * NN + col) = p;
            }
        }
        cs[w][lane] = ss;
        __syncthreads();
        if (w == 0) {
            floatx4 s4 = cs[0][lane] + cs[1][lane] + cs[2][lane] + cs[3][lane];
            float* np = nsq + col;
            atomicAdd(np + 0, s4[0]);
            atomicAdd(np + 1, s4[1]);
            atomicAdd(np + 2, s4[2]);
            atomicAdd(np + 3, s4[3]);
        }
    } else {  // ---- index role: row i — zero score row, sorted compaction ----
        const size_t i = (size_t)(bid - 1024);
        if (t < 64) ((floatx4*)(score + i * 256))[t] = (floatx4){0.f, 0.f, 0.f, 0.f};
        const floatx4* ar = (const floatx4*)(adj + i * NN) + 4 * t;
        floatx4 a0 = ar[0];
        floatx4 a1 = ar[1];
        floatx4 a2 = ar[2];
        floatx4 a3 = ar[3];
        unsigned mask = 0;
#pragma unroll
        for (int u = 0; u < 4; ++u) {
            floatx4 a = (u == 0) ? a0 : (u == 1) ? a1 : (u == 2) ? a2 : a3;
#pragma unroll
            for (int e = 0; e < 4; ++e)
                if (a[e] != 0.f) mask |= 1u << (4 * u + e);
        }
        const int h = __popc(mask);
        int sc = h;  // wave-inclusive scan
#pragma unroll
        for (int o = 1; o < 64; o <<= 1) {
            int v = __shfl_up(sc, o, 64);
            if (lane >= o) sc += v;
        }
        if (lane == 63) wtot[w] = sc;
        __syncthreads();
        int base = 0;
#pragma unroll
        for (int ww = 0; ww < 4; ++ww)
            if (ww < w) base += wtot[ww];
        int c = wtot[0] + wtot[1] + wtot[2] + wtot[3];
        if (c > 256) c = 256;
        if (t == 0) cnt[i] = c;
        int off = base + sc - h;  // exclusive prefix
        unsigned m = mask;
        while (m) {
            int b = __ffs(m) - 1;
            m &= m - 1;
            if (off < 256) idx[i * 256 + off] = (unsigned short)(16 * t + b);
            ++off;
        }
    }
}

// Partial scores for one (i-quad, slab), fp8 j-rows vs f16 x_i (r8-measured
// structure, met prediction — unchanged).
__global__ __launch_bounds__(256) void score_slab_fp8(const unsigned char* __restrict__ x8,
                                                      const short* __restrict__ xh,
                                                      const unsigned short* __restrict__ idx,
                                                      const int* __restrict__ cnt,
                                                      float* __restrict__ score) {
    const int t = threadIdx.x;
    const int lane = t & 63;
    const int w = t >> 6;
    const int g = lane >> 3;  // k-group within round
    const int sl = lane & 7;  // column sub-chunk
    const int col0 = blockIdx.x * SLABC;
    const size_t i = (size_t)blockIdx.y * 4 + w;
    const int c = cnt[i];
    const unsigned short* irow = idx + i * 256;

    const uintx4* xr = (const uintx4*)(xh + i * NN + col0);
    uintx4 xiA[4], xiB[4];
#pragma unroll
    for (int it = 0; it < 4; ++it) {
        const int m = it * 8 + sl;
        xiA[it] = xr[2 * m];
        xiB[it] = xr[2 * m + 1];
    }

    for (int r = 0; r * 8 < c; ++r) {
        const int k = r * 8 + g;
        const bool ok = k < c;
        const int kk = ok ? k : c - 1;
        const int j = irow[kk];
        const uintx4* rp = (const uintx4*)(x8 + (size_t)j * NN + col0);
        uintx4 v0 = rp[sl], v1 = rp[8 + sl], v2 = rp[16 + sl], v3 = rp[24 + sl];
        float d0 = 0.f, d1 = 0.f, d2 = 0.f, d3 = 0.f;
#pragma unroll
        for (int q = 0; q < 4; ++q) {
            const unsigned hA0 = (q < 2) ? xiA[0][2 * q] : xiB[0][2 * (q - 2)];
            const unsigned hA1 = (q < 2) ? xiA[0][2 * q + 1] : xiB[0][2 * (q - 2) + 1];
            d0 = fp8dot4(v0[q], hA0, hA1, d0);
            const unsigned hB0 = (q < 2) ? xiA[1][2 * q] : xiB[1][2 * (q - 2)];
            const unsigned hB1 = (q < 2) ? xiA[1][2 * q + 1] : xiB[1][2 * (q - 2) + 1];
            d1 = fp8dot4(v1[q], hB0, hB1, d1);
            const unsigned hC0 = (q < 2) ? xiA[2][2 * q] : xiB[2][2 * (q - 2)];
            const unsigned hC1 = (q < 2) ? xiA[2][2 * q + 1] : xiB[2][2 * (q - 2) + 1];
            d2 = fp8dot4(v2[q], hC0, hC1, d2);
            const unsigned hD0 = (q < 2) ? xiA[3][2 * q] : xiB[3][2 * (q - 2)];
            const unsigned hD1 = (q < 2) ? xiA[3][2 * q + 1] : xiB[3][2 * (q - 2) + 1];
            d3 = fp8dot4(v3[q], hD0, hD1, d3);
        }
        float d = (d0 + d1) + (d2 + d3);
        d += __shfl_xor(d, 1, 64);
        d += __shfl_xor(d, 2, 64);
        d += __shfl_xor(d, 4, 64);
        if (ok && sl == 0) atomicAdd(&score[i * 256 + k], d);
    }
}

// f16 fallback (r6-measured structure) for tight workspaces.
__global__ __launch_bounds__(256) void score_slab_f16(const short* __restrict__ xh,
                                                      const unsigned short* __restrict__ idx,
                                                      const int* __restrict__ cnt,
                                                      float* __restrict__ score) {
    const int t = threadIdx.x;
    const int lane = t & 63;
    const int w = t >> 6;
    const int g = lane >> 3;
    const int sl = lane & 7;
    const int col0 = blockIdx.x * SLABC;
    const size_t i = (size_t)blockIdx.y * 4 + w;
    const int c = cnt[i];
    const unsigned short* irow = idx + i * 256;

    const uintx4* xr = (const uintx4*)(xh + i * NN + col0);
    uintx4 xi[8];
#pragma unroll
    for (int it = 0; it < 8; ++it) xi[it] = xr[it * 8 + sl];

    for (int r = 0; r * 8 < c; ++r) {
        const int k = r * 8 + g;
        const bool ok = k < c;
        const int kk = ok ? k : c - 1;
        const int j = irow[kk];
        const uintx4* rp = (const uintx4*)(xh + (size_t)j * NN + col0);
        uintx4 v0 = rp[sl], v1 = rp[8 + sl], v2 = rp[16 + sl], v3 = rp[24 + sl];
        uintx4 v4 = rp[32 + sl], v5 = rp[40 + sl], v6 = rp[48 + sl], v7 = rp[56 + sl];
        float d0 = 0.f, d1 = 0.f, d2 = 0.f, d3 = 0.f;
#pragma unroll
        for (int u = 0; u < 4; ++u) {
            d0 = dot2acc(v0[u], xi[0][u], d0);
            d1 = dot2acc(v1[u], xi[1][u], d1);
            d2 = dot2acc(v2[u], xi[2][u], d2);
            d3 = dot2acc(v3[u], xi[3][u], d3);
            d0 = dot2acc(v4[u], xi[4][u], d0);
            d1 = dot2acc(v5[u], xi[5][u], d1);
            d2 = dot2acc(v6[u], xi[6][u], d2);
            d3 = dot2acc(v7[u], xi[7][u], d3);
        }
        float d = (d0 + d1) + (d2 + d3);
        d += __shfl_xor(d, 1, 64);
        d += __shfl_xor(d, 2, 64);
        d += __shfl_xor(d, 4, 64);
        if (ok && sl == 0) atomicAdd(&score[i * 256 + k], d);
    }
}

// PV for one (i-quad, slab) — EXACT r8-measured structure (74 µs, at the
// ~2.3 TB/s/XCD L2-gather ceiling). r9's rfl/pipeline variant measured WORSE
// (82 µs: readfirstlane+clamps added VALU, +8 VGPR cut occupancy). Wave w
// owns i = 4*by+w: per-wave softmax, p/j staged in LDS, lane owns cols
// [col0+8l, col0+8l+8), 4 k's in flight.
__global__ __launch_bounds__(256) void pv_slab(const short* __restrict__ xh,
                                               const float* __restrict__ nsq,
                                               const unsigned short* __restrict__ idx,
                                               const int* __restrict__ cnt,
                                               const float* __restrict__ score,
                                               const float* __restrict__ betaPtr,
                                               float* __restrict__ out) {
    __shared__ float svs[4][256];
    __shared__ unsigned short jds[4][256];
    const int t = threadIdx.x;
    const int lane = t & 63;
    const int w = t >> 6;
    const int col0 = blockIdx.x * SLABC;
    const size_t i = (size_t)blockIdx.y * 4 + w;
    const int c = cnt[i];
    const float beta = *betaPtr;
    const float ni = sqrtf(nsq[i]);

    float sreg[4];
    int jreg[4];
#pragma unroll
    for (int q = 0; q < 4; ++q) {
        const int k = lane + 64 * q;
        if (k < c) {
            const int j = idx[i * 256 + k];
            jreg[q] = j;
            sreg[q] = beta * score[i * 256 + k] / (ni * sqrtf(nsq[j]) + EPSV);
        } else {
            jreg[q] = 0;
            sreg[q] = -3.0e38f;
        }
    }
    float mx = fmaxf(fmaxf(sreg[0], sreg[1]), fmaxf(sreg[2], sreg[3]));
#pragma unroll
    for (int off = 32; off; off >>= 1) mx = fmaxf(mx, __shfl_xor(mx, off, 64));
    float sm = 0.f;
#pragma unroll
    for (int q = 0; q < 4; ++q) {
        const int k = lane + 64 * q;
        float e = (k < c) ? __expf(sreg[q] - mx) : 0.f;
        sreg[q] = e;
        sm += e;
    }
#pragma unroll
    for (int off = 32; off; off >>= 1) sm += __shfl_xor(sm, off, 64);
    const float inv = 1.f / sm;
#pragma unroll
    for (int q = 0; q < 4; ++q) {
        const int k = lane + 64 * q;
        svs[w][k] = sreg[q] * inv;
        jds[w][k] = (unsigned short)jreg[q];
    }
    __syncthreads();  // uniform; fences LDS

    float acc[8];
#pragma unroll
    for (int e = 0; e < 8; ++e) acc[e] = 0.f;
    const short* xcol = xh + col0 + lane * 8;
    int k = 0;
    for (; k + 4 <= c; k += 4) {
        const int j0 = jds[w][k], j1 = jds[w][k + 1];
        const int j2 = jds[w][k + 2], j3 = jds[w][k + 3];
        const float p0 = svs[w][k], p1 = svs[w][k + 1];
        const float p2 = svs[w][k + 2], p3 = svs[w][k + 3];
        uintx4 v0 = *(const uintx4*)(xcol + (size_t)j0 * NN);
        uintx4 v1 = *(const uintx4*)(xcol + (size_t)j1 * NN);
        uintx4 v2 = *(const uintx4*)(xcol + (size_t)j2 * NN);
        uintx4 v3 = *(const uintx4*)(xcol + (size_t)j3 * NN);
#pragma unroll
        for (int u = 0; u < 4; ++u) {
            union { unsigned x; half2t h; } c0, c1, c2, c3;
            c0.x = v0[u]; c1.x = v1[u]; c2.x = v2[u]; c3.x = v3[u];
            float a0 = acc[2 * u], a1 = acc[2 * u + 1];
            a0 = fmaf(p0, (float)c0.h[0], a0); a1 = fmaf(p0, (float)c0.h[1], a1);
            a0 = fmaf(p1, (float)c1.h[0], a0); a1 = fmaf(p1, (float)c1.h[1], a1);
            a0 = fmaf(p2, (float)c2.h[0], a0); a1 = fmaf(p2, (float)c2.h[1], a1);
            a0 = fmaf(p3, (float)c3.h[0], a0); a1 = fmaf(p3, (float)c3.h[1], a1);
            acc[2 * u] = a0; acc[2 * u + 1] = a1;
        }
    }
    for (; k < c; ++k) {
        const int j = jds[w][k];
        const float p = svs[w][k];
        uintx4 v = *(const uintx4*)(xcol + (size_t)j * NN);
#pragma unroll
        for (int u = 0; u < 4; ++u) {
            union { unsigned x; half2t h; } cc;
            cc.x = v[u];
            acc[2 * u] = fmaf(p, (float)cc.h[0], acc[2 * u]);
            acc[2 * u + 1] = fmaf(p, (float)cc.h[1], acc[2 * u + 1]);
        }
    }
    floatx4* op = (floatx4*)(out + i * NN + col0 + lane * 8);
    floatx4 o0 = {acc[0], acc[1], acc[2], acc[3]};
    floatx4 o1 = {acc[4], acc[5], acc[6], acc[7]};
    __builtin_nontemporal_store(o0, op + 0);
    __builtin_nontemporal_store(o1, op + 1);
}

extern "C" void kernel_launch(void* const* d_in, const int* in_sizes, int n_in,
                              void* d_out, int out_size, void* d_ws, size_t ws_size,
                              hipStream_t stream) {
    const float* x = (const float*)d_in[0];
    const float* adj = (const float*)d_in[1];
    const float* beta = (const float*)d_in[2];

    const size_t XH = (size_t)32 * 1024 * 1024;   // f16 x
    const size_t IX = (size_t)2 * 1024 * 1024;    // u16 idx [4096][256]
    const size_t SC = (size_t)4 * 1024 * 1024;    // f32 score [4096][256]
    const size_t XF8 = (size_t)16 * 1024 * 1024;  // fp8 x (optional, at end)
    const size_t base = XH + IX + SC + 2 * NN * sizeof(float);
    if (ws_size < base) return;  // ~38 MB
    const bool use_fp8 = ws_size >= base + XF8;  // ~54 MB

    char* ws = (char*)d_ws;
    short* xh = (short*)ws;
    unsigned short* idx = (unsigned short*)(ws + XH);
    float* score = (float*)(ws + XH + IX);
    float* nsq = (float*)(ws + XH + IX + SC);            // nsq+cnt adjacent:
    int* cnt = (int*)(ws + XH + IX + SC + NN * sizeof(float));  // one memset
    unsigned char* xf8 = use_fp8 ? (unsigned char*)(ws + base) : nullptr;

    (void)hipMemsetAsync(nsq, 0, 2 * NN * sizeof(float), stream);  // nsq + cnt
    prep<<<1024 + NN, 256, 0, stream>>>(x, adj, xh, xf8, nsq, idx, cnt, score);
    if (use_fp8)
        score_slab_fp8<<<dim3(NSLAB, NN / 4), 256, 0, stream>>>(xf8, xh, idx, cnt, score);
    else
        score_slab_f16<<<dim3(NSLAB, NN / 4), 256, 0, stream>>>(xh, idx, cnt, score);
    pv_slab<<<dim3(NSLAB, NN / 4), 256, 0, stream>>>(xh, nsq, idx, cnt, score, beta, (float*)d_out);
}

// Round 12
// 279.562 us; speedup vs baseline: 1.0834x; 1.0583x over previous
//
#include <hip/hip_runtime.h>
#include <stdint.h>

#define NN 4096
#define EPSV 1e-7f
#define SLABC 512          // columns per slab; f16 slab 4 MB, fp8 slab 2 MB (per-XCD L2-resident)
#define NSLAB (NN / SLABC) // 8 slabs = 8 XCDs

typedef short shortx4 __attribute__((ext_vector_type(4)));
typedef float floatx2 __attribute__((ext_vector_type(2)));
typedef float floatx4 __attribute__((ext_vector_type(4)));
typedef unsigned int uintx4 __attribute__((ext_vector_type(4)));
typedef _Float16 half2t __attribute__((ext_vector_type(2)));

static __device__ __forceinline__ short f2h(float f) {
    union { _Float16 h; short s; } c;
    c.h = (_Float16)f;
    return c.s;
}

// d += dot(2xf16(a), 2xf16(b)); folds to v_fma_mix_f32 (verified round 6 by
// VALU cycle accounting).
static __device__ __forceinline__ float dot2acc(unsigned a, unsigned b, float d) {
    union { unsigned u; half2t h; } ua, ub;
    ua.u = a; ub.u = b;
    d = fmaf((float)ua.h[0], (float)ub.h[0], d);
    return fmaf((float)ua.h[1], (float)ub.h[1], d);
}

// d += dot(4xfp8(v), 4xf16(h0:h1)); cvt_pk unpack + fma_mix.
static __device__ __forceinline__ float fp8dot4(unsigned v, unsigned h0, unsigned h1, float d) {
    floatx2 lo = __builtin_amdgcn_cvt_pk_f32_fp8(v, false);
    floatx2 hi = __builtin_amdgcn_cvt_pk_f32_fp8(v, true);
    union { unsigned u; half2t h; } a, b;
    a.u = h0; b.u = h1;
    d = fmaf(lo[0], (float)a.h[0], d);
    d = fmaf(lo[1], (float)a.h[1], d);
    d = fmaf(hi[0], (float)b.h[0], d);
    return fmaf(hi[1], (float)b.h[1], d);
}

// Fused prep: blocks [0,1024) cast x (f32) -> xh (f16) [+ xf8 fp8] + nsq col
// sumsq; blocks [1024,5120) zero score row + compact adj row (bid-1024) into
// a sorted index list. One launch: the two streaming passes overlap, and the
// score-zeroing rides along (replaces a 4 MB memset launch).
__global__ __launch_bounds__(256) void prep(const float* __restrict__ x,
                                            const float* __restrict__ adj,
                                            short* __restrict__ xh,
                                            unsigned char* __restrict__ xf8,  // may be null
                                            float* __restrict__ nsq,
                                            unsigned short* __restrict__ idx,
                                            int* __restrict__ cnt,
                                            float* __restrict__ score) {
    __shared__ floatx4 cs[4][64];
    __shared__ int wtot[4];
    const int bid = blockIdx.x;
    const int t = threadIdx.x;
    const int lane = t & 63;
    const int w = t >> 6;

    if (bid < 1024) {  // ---- cast role ----
        const int cb = (bid & 15) * 256;
        const int rb = (bid >> 4) * 64;
        const int col = cb + lane * 4;
        floatx4 ss = {0.f, 0.f, 0.f, 0.f};
#pragma unroll
        for (int i = 0; i < 16; ++i) {
            const int r = rb + w + i * 4;
            floatx4 v = *(const floatx4*)(x + (size_t)r * NN + col);
            ss += v * v;
            shortx4 o;
            o[0] = f2h(v[0]); o[1] = f2h(v[1]); o[2] = f2h(v[2]); o[3] = f2h(v[3]);
            *(shortx4*)(xh + (size_t)r * NN + col) = o;
            if (xf8) {  // uniform branch
                int p = __builtin_amdgcn_cvt_pk_fp8_f32(v[0], v[1], 0, false);
                p = __builtin_amdgcn_cvt_pk_fp8_f32(v[2], v[3], p, true);
                *(int*)(xf8 + (size_t)r * NN + col) = p;
            }
        }
        cs[w][lane] = ss;
        __syncthreads();
        if (w == 0) {
            floatx4 s4 = cs[0][lane] + cs[1][lane] + cs[2][lane] + cs[3][lane];
            float* np = nsq + col;
            atomicAdd(np + 0, s4[0]);
            atomicAdd(np + 1, s4[1]);
            atomicAdd(np + 2, s4[2]);
            atomicAdd(np + 3, s4[3]);
        }
    } else {  // ---- index role: row i — zero score row, sorted compaction ----
        const size_t i = (size_t)(bid - 1024);
        if (t < 64) ((floatx4*)(score + i * 256))[t] = (floatx4){0.f, 0.f, 0.f, 0.f};
        const floatx4* ar = (const floatx4*)(adj + i * NN) + 4 * t;
        floatx4 a0 = ar[0];
        floatx4 a1 = ar[1];
        floatx4 a2 = ar[2];
        floatx4 a3 = ar[3];
        unsigned mask = 0;
#pragma unroll
        for (int u = 0; u < 4; ++u) {
            floatx4 a = (u == 0) ? a0 : (u == 1) ? a1 : (u == 2) ? a2 : a3;
#pragma unroll
            for (int e = 0; e < 4; ++e)
                if (a[e] != 0.f) mask |= 1u << (4 * u + e);
        }
        const int h = __popc(mask);
        int sc = h;  // wave-inclusive scan
#pragma unroll
        for (int o = 1; o < 64; o <<= 1) {
            int v = __shfl_up(sc, o, 64);
            if (lane >= o) sc += v;
        }
        if (lane == 63) wtot[w] = sc;
        __syncthreads();
        int base = 0;
#pragma unroll
        for (int ww = 0; ww < 4; ++ww)
            if (ww < w) base += wtot[ww];
        int c = wtot[0] + wtot[1] + wtot[2] + wtot[3];
        if (c > 256) c = 256;
        if (t == 0) cnt[i] = c;
        int off = base + sc - h;  // exclusive prefix
        unsigned m = mask;
        while (m) {
            int b = __ffs(m) - 1;
            m &= m - 1;
            if (off < 256) idx[i * 256 + off] = (unsigned short)(16 * t + b);
            ++off;
        }
    }
}

// Partial scores for one (i-quad, slab), fp8 j-rows vs f16 x_i.
// x_i lives in LDS (wave-private row, no barrier — wave-coherent via lgkmcnt)
// and is RE-READ each round instead of pinned in 32 VGPRs. Frees ~24 VGPR ->
// more resident waves to hide the L2 gather latency (r10: 52 VGPR / 33%
// occupancy vs pv's 28 / 66%). Bank math: the 8 distinct sl addresses per
// ds_read_b128 are 32 B apart -> 2-way aliasing only (free), same-address
// lanes broadcast. LICM blocker: a VOLATILE LDS read of a zero slot each
// round poisons the xl index, so the (loop-invariant) ds_reads cannot be
// hoisted back into registers. Pure C — no inline asm (r11's asm variant was
// the prime suspect for the build failure).
__global__ __launch_bounds__(256) void score_slab_fp8(const unsigned char* __restrict__ x8,
                                                      const short* __restrict__ xh,
                                                      const unsigned short* __restrict__ idx,
                                                      const int* __restrict__ cnt,
                                                      float* __restrict__ score) {
    __shared__ __align__(16) short xi_lds[4][512];
    __shared__ int zslot[4];
    const int t = threadIdx.x;
    const int lane = t & 63;
    const int w = t >> 6;
    const int g = lane >> 3;  // k-group within round
    const int sl = lane & 7;  // column sub-chunk
    const int col0 = blockIdx.x * SLABC;
    const size_t i = (size_t)blockIdx.y * 4 + w;
    const int c = cnt[i];
    const unsigned short* irow = idx + i * 256;

    // stage x_i slab row (1 KB) into this wave's LDS row: 16 B per lane
    ((uintx4*)xi_lds[w])[lane] = ((const uintx4*)(xh + i * NN + col0))[lane];
    if (lane == 0) zslot[w] = 0;
    const uintx4* xl = (const uintx4*)xi_lds[w];

    for (int r = 0; r * 8 < c; ++r) {
        const int k = r * 8 + g;
        const bool ok = k < c;
        const int kk = ok ? k : c - 1;
        const int j = irow[kk];
        const uintx4* rp = (const uintx4*)(x8 + (size_t)j * NN + col0);
        uintx4 v0 = rp[sl], v1 = rp[8 + sl], v2 = rp[16 + sl], v3 = rp[24 + sl];

        // volatile zero read (broadcast, ~6 cyc): defeats LICM of the ds_reads
        const int b0 = *(volatile int*)&zslot[w];

        float d0 = 0.f, d1 = 0.f, d2 = 0.f, d3 = 0.f;
#pragma unroll
        for (int n = 0; n < 4; ++n) {
            const int m = 2 * (n * 8 + sl) + b0;  // uintx4 index of chunk
            uintx4 xa = xl[m];      // f16 cols [16c, 16c+8) of chunk
            uintx4 xb = xl[m + 1];  // f16 cols [16c+8, 16c+16)
            uintx4 v = (n == 0) ? v0 : (n == 1) ? v1 : (n == 2) ? v2 : v3;
            d0 = fp8dot4(v[0], xa[0], xa[1], d0);
            d1 = fp8dot4(v[1], xa[2], xa[3], d1);
            d2 = fp8dot4(v[2], xb[0], xb[1], d2);
            d3 = fp8dot4(v[3], xb[2], xb[3], d3);
        }
        float d = (d0 + d1) + (d2 + d3);
        d += __shfl_xor(d, 1, 64);
        d += __shfl_xor(d, 2, 64);
        d += __shfl_xor(d, 4, 64);
        if (ok && sl == 0) atomicAdd(&score[i * 256 + k], d);
    }
}

// f16 fallback (r6-measured structure) for tight workspaces.
__global__ __launch_bounds__(256) void score_slab_f16(const short* __restrict__ xh,
                                                      const unsigned short* __restrict__ idx,
                                                      const int* __restrict__ cnt,
                                                      float* __restrict__ score) {
    const int t = threadIdx.x;
    const int lane = t & 63;
    const int w = t >> 6;
    const int g = lane >> 3;
    const int sl = lane & 7;
    const int col0 = blockIdx.x * SLABC;
    const size_t i = (size_t)blockIdx.y * 4 + w;
    const int c = cnt[i];
    const unsigned short* irow = idx + i * 256;

    const uintx4* xr = (const uintx4*)(xh + i * NN + col0);
    uintx4 xi[8];
#pragma unroll
    for (int it = 0; it < 8; ++it) xi[it] = xr[it * 8 + sl];

    for (int r = 0; r * 8 < c; ++r) {
        const int k = r * 8 + g;
        const bool ok = k < c;
        const int kk = ok ? k : c - 1;
        const int j = irow[kk];
        const uintx4* rp = (const uintx4*)(xh + (size_t)j * NN + col0);
        uintx4 v0 = rp[sl], v1 = rp[8 + sl], v2 = rp[16 + sl], v3 = rp[24 + sl];
        uintx4 v4 = rp[32 + sl], v5 = rp[40 + sl], v6 = rp[48 + sl], v7 = rp[56 + sl];
        float d0 = 0.f, d1 = 0.f, d2 = 0.f, d3 = 0.f;
#pragma unroll
        for (int u = 0; u < 4; ++u) {
            d0 = dot2acc(v0[u], xi[0][u], d0);
            d1 = dot2acc(v1[u], xi[1][u], d1);
            d2 = dot2acc(v2[u], xi[2][u], d2);
            d3 = dot2acc(v3[u], xi[3][u], d3);
            d0 = dot2acc(v4[u], xi[4][u], d0);
            d1 = dot2acc(v5[u], xi[5][u], d1);
            d2 = dot2acc(v6[u], xi[6][u], d2);
            d3 = dot2acc(v7[u], xi[7][u], d3);
        }
        float d = (d0 + d1) + (d2 + d3);
        d += __shfl_xor(d, 1, 64);
        d += __shfl_xor(d, 2, 64);
        d += __shfl_xor(d, 4, 64);
        if (ok && sl == 0) atomicAdd(&score[i * 256 + k], d);
    }
}

// PV for one (i-quad, slab) — EXACT r8-measured structure (74 µs, at the
// ~2.3 TB/s/XCD L2-gather ceiling; r9's rfl/pipeline variant measured worse).
__global__ __launch_bounds__(256) void pv_slab(const short* __restrict__ xh,
                                               const float* __restrict__ nsq,
                                               const unsigned short* __restrict__ idx,
                                               const int* __restrict__ cnt,
                                               const float* __restrict__ score,
                                               const float* __restrict__ betaPtr,
                                               float* __restrict__ out) {
    __shared__ float svs[4][256];
    __shared__ unsigned short jds[4][256];
    const int t = threadIdx.x;
    const int lane = t & 63;
    const int w = t >> 6;
    const int col0 = blockIdx.x * SLABC;
    const size_t i = (size_t)blockIdx.y * 4 + w;
    const int c = cnt[i];
    const float beta = *betaPtr;
    const float ni = sqrtf(nsq[i]);

    float sreg[4];
    int jreg[4];
#pragma unroll
    for (int q = 0; q < 4; ++q) {
        const int k = lane + 64 * q;
        if (k < c) {
            const int j = idx[i * 256 + k];
            jreg[q] = j;
            sreg[q] = beta * score[i * 256 + k] / (ni * sqrtf(nsq[j]) + EPSV);
        } else {
            jreg[q] = 0;
            sreg[q] = -3.0e38f;
        }
    }
    float mx = fmaxf(fmaxf(sreg[0], sreg[1]), fmaxf(sreg[2], sreg[3]));
#pragma unroll
    for (int off = 32; off; off >>= 1) mx = fmaxf(mx, __shfl_xor(mx, off, 64));
    float sm = 0.f;
#pragma unroll
    for (int q = 0; q < 4; ++q) {
        const int k = lane + 64 * q;
        float e = (k < c) ? __expf(sreg[q] - mx) : 0.f;
        sreg[q] = e;
        sm += e;
    }
#pragma unroll
    for (int off = 32; off; off >>= 1) sm += __shfl_xor(sm, off, 64);
    const float inv = 1.f / sm;
#pragma unroll
    for (int q = 0; q < 4; ++q) {
        const int k = lane + 64 * q;
        svs[w][k] = sreg[q] * inv;
        jds[w][k] = (unsigned short)jreg[q];
    }
    __syncthreads();  // uniform; fences LDS

    float acc[8];
#pragma unroll
    for (int e = 0; e < 8; ++e) acc[e] = 0.f;
    const short* xcol = xh + col0 + lane * 8;
    int k = 0;
    for (; k + 4 <= c; k += 4) {
        const int j0 = jds[w][k], j1 = jds[w][k + 1];
        const int j2 = jds[w][k + 2], j3 = jds[w][k + 3];
        const float p0 = svs[w][k], p1 = svs[w][k + 1];
        const float p2 = svs[w][k + 2], p3 = svs[w][k + 3];
        uintx4 v0 = *(const uintx4*)(xcol + (size_t)j0 * NN);
        uintx4 v1 = *(const uintx4*)(xcol + (size_t)j1 * NN);
        uintx4 v2 = *(const uintx4*)(xcol + (size_t)j2 * NN);
        uintx4 v3 = *(const uintx4*)(xcol + (size_t)j3 * NN);
#pragma unroll
        for (int u = 0; u < 4; ++u) {
            union { unsigned x; half2t h; } c0, c1, c2, c3;
            c0.x = v0[u]; c1.x = v1[u]; c2.x = v2[u]; c3.x = v3[u];
            float a0 = acc[2 * u], a1 = acc[2 * u + 1];
            a0 = fmaf(p0, (float)c0.h[0], a0); a1 = fmaf(p0, (float)c0.h[1], a1);
            a0 = fmaf(p1, (float)c1.h[0], a0); a1 = fmaf(p1, (float)c1.h[1], a1);
            a0 = fmaf(p2, (float)c2.h[0], a0); a1 = fmaf(p2, (float)c2.h[1], a1);
            a0 = fmaf(p3, (float)c3.h[0], a0); a1 = fmaf(p3, (float)c3.h[1], a1);
            acc[2 * u] = a0; acc[2 * u + 1] = a1;
        }
    }
    for (; k < c; ++k) {
        const int j = jds[w][k];
        const float p = svs[w][k];
        uintx4 v = *(const uintx4*)(xcol + (size_t)j * NN);
#pragma unroll
        for (int u = 0; u < 4; ++u) {
            union { unsigned x; half2t h; } cc;
            cc.x = v[u];
            acc[2 * u] = fmaf(p, (float)cc.h[0], acc[2 * u]);
            acc[2 * u + 1] = fmaf(p, (float)cc.h[1], acc[2 * u + 1]);
        }
    }
    floatx4* op = (floatx4*)(out + i * NN + col0 + lane * 8);
    floatx4 o0 = {acc[0], acc[1], acc[2], acc[3]};
    floatx4 o1 = {acc[4], acc[5], acc[6], acc[7]};
    __builtin_nontemporal_store(o0, op + 0);
    __builtin_nontemporal_store(o1, op + 1);
}

extern "C" void kernel_launch(void* const* d_in, const int* in_sizes, int n_in,
                              void* d_out, int out_size, void* d_ws, size_t ws_size,
                              hipStream_t stream) {
    const float* x = (const float*)d_in[0];
    const float* adj = (const float*)d_in[1];
    const float* beta = (const float*)d_in[2];

    const size_t XH = (size_t)32 * 1024 * 1024;   // f16 x
    const size_t IX = (size_t)2 * 1024 * 1024;    // u16 idx [4096][256]
    const size_t SC = (size_t)4 * 1024 * 1024;    // f32 score [4096][256]
    const size_t XF8 = (size_t)16 * 1024 * 1024;  // fp8 x (optional, at end)
    const size_t base = XH + IX + SC + 2 * NN * sizeof(float);
    if (ws_size < base) return;  // ~38 MB
    const bool use_fp8 = ws_size >= base + XF8;  // ~54 MB

    char* ws = (char*)d_ws;
    short* xh = (short*)ws;
    unsigned short* idx = (unsigned short*)(ws + XH);
    float* score = (float*)(ws + XH + IX);
    float* nsq = (float*)(ws + XH + IX + SC);            // nsq+cnt adjacent:
    int* cnt = (int*)(ws + XH + IX + SC + NN * sizeof(float));  // one memset
    unsigned char* xf8 = use_fp8 ? (unsigned char*)(ws + base) : nullptr;

    (void)hipMemsetAsync(nsq, 0, 2 * NN * sizeof(float), stream);  // nsq + cnt
    prep<<<1024 + NN, 256, 0, stream>>>(x, adj, xh, xf8, nsq, idx, cnt, score);
    if (use_fp8)
        score_slab_fp8<<<dim3(NSLAB, NN / 4), 256, 0, stream>>>(xf8, xh, idx, cnt, score);
    else
        score_slab_f16<<<dim3(NSLAB, NN / 4), 256, 0, stream>>>(xh, idx, cnt, score);
    pv_slab<<<dim3(NSLAB, NN / 4), 256, 0, stream>>>(xh, nsq, idx, cnt, score, beta, (float*)d_out);
}